// Round 8
// baseline (2427.236 us; speedup 1.0000x reference)
//
#include <hip/hip_runtime.h>
#include <float.h>
#include <math.h>

// Problem constants
#define B_ 16
#define N_ 4096
#define S_ 1024
#define K_ 32
#define NBS (B_ * S_)        // 16384
#define NEWXYZ_FLOATS (B_ * S_ * 3)  // 49152
#define AST 68               // act row stride (67 in-ch + 1 zero pad)
#define AQ (K_ * AST)        // 2176 floats per query
#define QB 4                 // queries per pass-block

// ---------------- helpers ----------------

__device__ __forceinline__ float sqdist3(float x, float y, float z,
                                         float cx, float cy, float cz) {
#pragma clang fp contract(off)
  float dx = x - cx, dy = y - cy, dz = z - cz;
  float s = dx * dx;
  s = s + dy * dy;
  s = s + dz * dz;
  return s;
}

__device__ __forceinline__ float knn_dist(float c2, float cx, float cy, float cz,
                                          float x, float y, float z) {
#pragma clang fp contract(off)
  float dot = cx * x; dot = dot + cy * y; dot = dot + cz * z;
  float x2 = x * x;   x2 = x2 + y * y;   x2 = x2 + z * z;
  float d = c2 - 2.0f * dot;
  d = d + x2;
  return d;
}

// ---- DPP cross-lane (gfx9: row_shr:N=0x110|N, row_bcast15=0x142, row_bcast31=0x143) ----
template <int CTRL>
__device__ __forceinline__ float dpp_f(float v, float oldv) {
  return __int_as_float(__builtin_amdgcn_update_dpp(
      __float_as_int(oldv), __float_as_int(v), CTRL, 0xF, 0xF, false));
}
template <int CTRL>
__device__ __forceinline__ int dpp_i(int v, int oldv) {
  return __builtin_amdgcn_update_dpp(oldv, v, CTRL, 0xF, 0xF, false);
}

template <int CTRL>
__device__ __forceinline__ void fps_combine2(float& val, int& idx) {
  const float tv = dpp_f<CTRL>(val, -1.0f);
  const int ti = dpp_i<CTRL>(idx, 0x7fffffff);
  const bool take = (tv > val) || (tv == val && ti < idx);
  val = take ? tv : val;
  idx = take ? ti : idx;
}

// ---------------- FPS: one block (256 thr = 4 waves) per batch ----------------
// Software-pipelined: coords live in float4 p4[16] regs; the NEXT step's 16
// ds_read_b128 are issued after the DPP/rec-write but BEFORE __syncthreads
// (coords don't depend on the new centroid), so they drain under the
// barrier+resolve serial tail. sched_barrier(0) pins the load placement.
// Bit-exact vs numpy: contract(off) distances, same op order, first-index
// argmax tie-break (ascending index scan; min-idx combine).
__global__ __launch_bounds__(256, 1) void fps_kernel(
    const float* __restrict__ xyz, float* __restrict__ newxyz) {
  const int b = blockIdx.x;
  const int t = threadIdx.x;
  __shared__ float4 sp[N_];      // 64 KB coords (x,y,z,0)
  __shared__ float2 rec[2][4];   // [parity][wave] = (val, idxbits)
  const float* xb = xyz + (size_t)b * N_ * 3;
  for (int p = t; p < N_; p += 256) {
    sp[p] = make_float4(xb[p * 3 + 0], xb[p * 3 + 1], xb[p * 3 + 2], 0.0f);
  }
  float dist[16];
#pragma unroll
  for (int j = 0; j < 16; ++j) dist[j] = 1e10f;
  __syncthreads();
  // prologue: load this thread's 16 coords into registers
  float4 p4[16];
#pragma unroll
  for (int j = 0; j < 16; ++j) p4[j] = sp[j * 256 + t];
  float4 c0 = sp[0];
  float cx = c0.x, cy = c0.y, cz = c0.z;  // farthest init = point 0
  for (int s = 0; s < S_; ++s) {
    if (t == 0) {
      float* o = newxyz + ((size_t)b * S_ + s) * 3;
      o[0] = cx; o[1] = cy; o[2] = cz;
    }
    // distances from register-resident coords (pure VALU, independent)
    float dd[16];
#pragma unroll
    for (int j = 0; j < 16; ++j) {
      dd[j] = sqdist3(p4[j].x, p4[j].y, p4[j].z, cx, cy, cz);
    }
    __builtin_amdgcn_sched_barrier(0);
    // register-only min + local argmax (ascending j -> first on tie)
    float best = -1.0f;
    int bi = 0;
#pragma unroll
    for (int j = 0; j < 16; ++j) {
      const float nd = fminf(dist[j], dd[j]);
      dist[j] = nd;
      const bool take = nd > best;
      best = take ? nd : best;
      bi = take ? (j * 256 + t) : bi;
    }
    // DPP wave argmax (result complete in lane 63)
    fps_combine2<0x111>(best, bi);
    fps_combine2<0x112>(best, bi);
    fps_combine2<0x114>(best, bi);
    fps_combine2<0x118>(best, bi);
    fps_combine2<0x142>(best, bi);
    fps_combine2<0x143>(best, bi);
    const float wv = __int_as_float(__builtin_amdgcn_readlane(__float_as_int(best), 63));
    const int wi = __builtin_amdgcn_readlane(bi, 63);
    const int par = s & 1;
    if ((t & 63) == 0) {
      rec[par][t >> 6] = make_float2(wv, __int_as_float(wi));
    }
    // issue NEXT step's coord loads here: they hide under barrier + resolve
    __builtin_amdgcn_sched_barrier(0);
#pragma unroll
    for (int j = 0; j < 16; ++j) p4[j] = sp[j * 256 + t];
    __builtin_amdgcn_sched_barrier(0);
    __syncthreads();
    // all threads resolve the 4 wave candidates redundantly
    float2 r0 = rec[par][0];
    float bv = r0.x;
    int bj = __float_as_int(r0.y);
#pragma unroll
    for (int w = 1; w < 4; ++w) {
      const float2 r = rec[par][w];
      const int iw = __float_as_int(r.y);
      const bool take = (r.x > bv) || (r.x == bv && iw < bj);
      bv = take ? r.x : bv;
      bj = take ? iw : bj;
    }
    const float4 c = sp[bj];  // broadcast read
    cx = c.x; cy = c.y; cz = c.z;
  }
}

// ---------------- KNN: one wave per query, 4 queries/block ----------------
__global__ __launch_bounds__(256, 2) void knn_kernel(
    const float* __restrict__ xyz, const float* __restrict__ newxyz,
    int* __restrict__ knn_idx) {
  const int bs0 = blockIdx.x * 4;
  const int b = bs0 >> 10;
  const int t = threadIdx.x;
  const int wave = t >> 6;
  const int lane = t & 63;
  __shared__ float sxx[N_];
  __shared__ float sxy[N_];
  __shared__ float sxz[N_];
  const float* xb = xyz + (size_t)b * N_ * 3;
  for (int p = t; p < N_; p += 256) {
    sxx[p] = xb[p * 3 + 0];
    sxy[p] = xb[p * 3 + 1];
    sxz[p] = xb[p * 3 + 2];
  }
  __syncthreads();
  const int bs = bs0 + wave;
  const float cx = newxyz[(size_t)bs * 3 + 0];
  const float cy = newxyz[(size_t)bs * 3 + 1];
  const float cz = newxyz[(size_t)bs * 3 + 2];
  float c2;
  {
#pragma clang fp contract(off)
    float s = cx * cx;
    s = s + cy * cy;
    s = s + cz * cz;
    c2 = s;
  }
  float d[64];
  float gval[8];
  int gidx[8];
#pragma unroll
  for (int g = 0; g < 8; ++g) {
    float gv = FLT_MAX;
    int gi = g * 8;
#pragma unroll
    for (int q = 0; q < 8; ++q) {
      const int j = g * 8 + q;
      const int p = j * 64 + lane;
      const float dd = knn_dist(c2, cx, cy, cz, sxx[p], sxy[p], sxz[p]);
      d[j] = dd;
      if (dd < gv) { gv = dd; gi = j; }
    }
    gval[g] = gv; gidx[g] = gi;
  }
  int* krow = knn_idx + (size_t)bs * K_;
  for (int it = 0; it < K_; ++it) {
    float best = gval[0];
    int bj = gidx[0];
#pragma unroll
    for (int g = 1; g < 8; ++g) {
      if (gval[g] < best || (gval[g] == best && gidx[g] < bj)) { best = gval[g]; bj = gidx[g]; }
    }
    int bidx = bj * 64 + lane;
#pragma unroll
    for (int off = 32; off >= 1; off >>= 1) {
      const float ov = __shfl_xor(best, off);
      const int oi = __shfl_xor(bidx, off);
      if (ov < best || (ov == best && oi < bidx)) { best = ov; bidx = oi; }
    }
    if (lane == 0) krow[it] = bidx;
    if (lane == (bidx & 63)) {
      const int jl = bidx >> 6;
      const int gg = jl >> 3;
      const int qq = jl & 7;
#pragma unroll
      for (int g = 0; g < 8; ++g) {
        if (g == gg) {
#pragma unroll
          for (int q = 0; q < 8; ++q) {
            d[g * 8 + q] = (q == qq) ? FLT_MAX : d[g * 8 + q];
          }
          float gv = FLT_MAX;
          int gi = g * 8;
#pragma unroll
          for (int q = 0; q < 8; ++q) {
            const int j = g * 8 + q;
            if (d[j] < gv) { gv = d[j]; gi = j; }
          }
          gval[g] = gv; gidx[g] = gi;
        }
      }
    }
  }
}

// ---------------- Pass building blocks (QB=4, register-blocked) ----------------
// Thread map: q = t>>6 (wave = query), r = t&63, kslot = r>>3, g = r&7.
// Each thread: 4 points k = kslot*4+i, 8 channels ch = g*8+j. acc[4][8] regs.

// stage weights: w0 (67,64) padded to 68 rows (row 67 = 0)
__device__ __forceinline__ void loadw0p(float* __restrict__ wbuf,
                                        const float* __restrict__ w0, int t) {
  for (int i = t; i < 68 * 64; i += 256) {
    const int c = i >> 6;
    wbuf[i] = (c < 67) ? w0[i] : 0.0f;
  }
}
__device__ __forceinline__ void loadw64(float* __restrict__ wbuf,
                                        const float* __restrict__ w, int t) {
  for (int i = t; i < 64 * 64; i += 256) wbuf[i] = w[i];
}
// w2 (64,128) -> wbuf[64][64] = columns ofs..ofs+63
__device__ __forceinline__ void loadw_half(float* __restrict__ wbuf,
                                           const float* __restrict__ w2, int ofs, int t) {
  for (int i = t; i < 64 * 64; i += 256) {
    const int c = i >> 6, j = i & 63;
    wbuf[i] = w2[c * 128 + ofs + j];
  }
}

// gather + center + concat for 4 queries -> act[QB][32][AST], col 67 zeroed
__device__ __forceinline__ void build4(float* __restrict__ act,
    const float* __restrict__ xyz, const float* __restrict__ points,
    const int* __restrict__ knn_idx, const float* __restrict__ newxyz,
    int bs0, int t) {
  const int b = bs0 >> 10;
  for (int i = t; i < QB * K_ * AST; i += 256) {
    const int q = i / AQ;
    const int rem = i - q * AQ;
    const int k = rem / AST;
    const int c = rem - k * AST;
    const int bs = bs0 + q;
    const int p = knn_idx[(size_t)bs * K_ + k];
    float v;
    if (c < 3) {
      v = xyz[((size_t)b * N_ + p) * 3 + c] - newxyz[(size_t)bs * 3 + c];
    } else if (c < 67) {
      v = points[((size_t)b * N_ + p) * 64 + (c - 3)];
    } else {
      v = 0.0f;
    }
    act[i] = v;
  }
}

// acc = actq x wbuf + bias ; CQ = input c-quads (17 for 68-pad, 16 for 64)
template <int CQ>
__device__ __forceinline__ void mm_unit(const float* __restrict__ actq,
    const float* __restrict__ wbuf, const float* __restrict__ bias,
    float acc[4][8], int kslot, int g) {
#pragma unroll
  for (int j = 0; j < 8; ++j) {
    const float bj = bias[g * 8 + j];
#pragma unroll
    for (int i = 0; i < 4; ++i) acc[i][j] = bj;
  }
  for (int qd = 0; qd < CQ; ++qd) {
    float4 a[4];
#pragma unroll
    for (int i = 0; i < 4; ++i)
      a[i] = *(const float4*)&actq[(kslot * 4 + i) * AST + qd * 4];
    float4 w0v[4], w1v[4];
#pragma unroll
    for (int cc = 0; cc < 4; ++cc) {
      w0v[cc] = *(const float4*)&wbuf[(qd * 4 + cc) * 64 + g * 8];
      w1v[cc] = *(const float4*)&wbuf[(qd * 4 + cc) * 64 + g * 8 + 4];
    }
#pragma unroll
    for (int cc = 0; cc < 4; ++cc) {
#pragma unroll
      for (int i = 0; i < 4; ++i) {
        const float x = (cc == 0) ? a[i].x : (cc == 1) ? a[i].y
                        : (cc == 2) ? a[i].z : a[i].w;
        acc[i][0] += x * w0v[cc].x;
        acc[i][1] += x * w0v[cc].y;
        acc[i][2] += x * w0v[cc].z;
        acc[i][3] += x * w0v[cc].w;
        acc[i][4] += x * w1v[cc].x;
        acc[i][5] += x * w1v[cc].y;
        acc[i][6] += x * w1v[cc].z;
        acc[i][7] += x * w1v[cc].w;
      }
    }
  }
}

// BN-norm + relu acc in registers, write into act rows (caller barriers around)
__device__ __forceinline__ void write_normed(float* __restrict__ actq,
    const float acc[4][8], const float* __restrict__ scale,
    const float* __restrict__ shift, int kslot, int g) {
  float sc[8], sh[8];
#pragma unroll
  for (int j = 0; j < 8; ++j) { sc[j] = scale[g * 8 + j]; sh[j] = shift[g * 8 + j]; }
#pragma unroll
  for (int i = 0; i < 4; ++i) {
    float4 lo, hi;
    lo.x = fmaxf(acc[i][0] * sc[0] + sh[0], 0.0f);
    lo.y = fmaxf(acc[i][1] * sc[1] + sh[1], 0.0f);
    lo.z = fmaxf(acc[i][2] * sc[2] + sh[2], 0.0f);
    lo.w = fmaxf(acc[i][3] * sc[3] + sh[3], 0.0f);
    hi.x = fmaxf(acc[i][4] * sc[4] + sh[4], 0.0f);
    hi.y = fmaxf(acc[i][5] * sc[5] + sh[5], 0.0f);
    hi.z = fmaxf(acc[i][6] * sc[6] + sh[6], 0.0f);
    hi.w = fmaxf(acc[i][7] * sc[7] + sh[7], 0.0f);
    *(float4*)&actq[(kslot * 4 + i) * AST + g * 8] = lo;
    *(float4*)&actq[(kslot * 4 + i) * AST + g * 8 + 4] = hi;
  }
}

// per-channel sum/sumsq over 32 points: 4 in-thread + shfl tree over kslot lanes
__device__ __forceinline__ void stats_reduce(const float acc[4][8],
    float* __restrict__ psum, float* __restrict__ psq, int bs, int ofs, int r) {
  float s[8], ss[8];
#pragma unroll
  for (int j = 0; j < 8; ++j) {
    s[j] = ((acc[0][j] + acc[1][j]) + acc[2][j]) + acc[3][j];
    ss[j] = ((acc[0][j] * acc[0][j] + acc[1][j] * acc[1][j]) +
             acc[2][j] * acc[2][j]) + acc[3][j] * acc[3][j];
  }
#pragma unroll
  for (int m = 8; m <= 32; m <<= 1) {
#pragma unroll
    for (int j = 0; j < 8; ++j) {
      s[j] += __shfl_xor(s[j], m);
      ss[j] += __shfl_xor(ss[j], m);
    }
  }
  if (r < 8) {  // kslot==0 lanes; g == r
#pragma unroll
    for (int j = 0; j < 8; ++j) {
      psum[(size_t)bs * 128 + ofs + r * 8 + j] = s[j];
      psq[(size_t)bs * 128 + ofs + r * 8 + j] = ss[j];
    }
  }
}

// per-channel raw max/min over 32 points (for the final fused max-pool)
__device__ __forceinline__ void minmax_reduce(const float acc[4][8],
    float* __restrict__ maxraw, float* __restrict__ minbuf, int bs, int ofs, int r) {
  float mx[8], mn[8];
#pragma unroll
  for (int j = 0; j < 8; ++j) {
    mx[j] = fmaxf(fmaxf(acc[0][j], acc[1][j]), fmaxf(acc[2][j], acc[3][j]));
    mn[j] = fminf(fminf(acc[0][j], acc[1][j]), fminf(acc[2][j], acc[3][j]));
  }
#pragma unroll
  for (int m = 8; m <= 32; m <<= 1) {
#pragma unroll
    for (int j = 0; j < 8; ++j) {
      mx[j] = fmaxf(mx[j], __shfl_xor(mx[j], m));
      mn[j] = fminf(mn[j], __shfl_xor(mn[j], m));
    }
  }
  if (r < 8) {
#pragma unroll
    for (int j = 0; j < 8; ++j) {
      maxraw[(size_t)bs * 128 + ofs + r * 8 + j] = mx[j];
      minbuf[(size_t)bs * 128 + ofs + r * 8 + j] = mn[j];
    }
  }
}

// ---------------- Pass A: layer0 stats ----------------
__global__ __launch_bounds__(256) void passA_kernel(
    const float* __restrict__ xyz, const float* __restrict__ points,
    const float* __restrict__ newxyz, const int* __restrict__ knn_idx,
    const float* __restrict__ w0, const float* __restrict__ b0,
    float* __restrict__ psum, float* __restrict__ psq) {
  __shared__ float act[QB * AQ];
  __shared__ float wbuf[68 * 64];
  const int bs0 = blockIdx.x * QB, t = threadIdx.x;
  build4(act, xyz, points, knn_idx, newxyz, bs0, t);
  loadw0p(wbuf, w0, t);
  __syncthreads();
  const int q = t >> 6, r = t & 63, ks = r >> 3, g = r & 7;
  float acc[4][8];
  mm_unit<17>(act + q * AQ, wbuf, b0, acc, ks, g);
  stats_reduce(acc, psum, psq, bs0 + q, 0, r);
}

// ---------------- Pass B: recompute layer0, layer1 stats ----------------
__global__ __launch_bounds__(256) void passB_kernel(
    const float* __restrict__ xyz, const float* __restrict__ points,
    const float* __restrict__ newxyz, const int* __restrict__ knn_idx,
    const float* __restrict__ w0, const float* __restrict__ b0,
    const float* __restrict__ w1, const float* __restrict__ b1,
    const float* __restrict__ scales, const float* __restrict__ shifts,
    float* __restrict__ psum, float* __restrict__ psq) {
  __shared__ float act[QB * AQ];
  __shared__ float wbuf[68 * 64];
  const int bs0 = blockIdx.x * QB, t = threadIdx.x;
  build4(act, xyz, points, knn_idx, newxyz, bs0, t);
  loadw0p(wbuf, w0, t);
  __syncthreads();
  const int q = t >> 6, r = t & 63, ks = r >> 3, g = r & 7;
  float* actq = act + q * AQ;
  float acc[4][8];
  mm_unit<17>(actq, wbuf, b0, acc, ks, g);
  __syncthreads();  // all input reads done before in-place overwrite
  write_normed(actq, acc, scales, shifts, ks, g);
  loadw64(wbuf, w1, t);
  __syncthreads();
  mm_unit<16>(actq, wbuf, b1, acc, ks, g);
  stats_reduce(acc, psum, psq, bs0 + q, 0, r);
}

// ---------------- Pass C: recompute through layer2; stats + min/max ----------------
__global__ __launch_bounds__(256) void passC_kernel(
    const float* __restrict__ xyz, const float* __restrict__ points,
    const float* __restrict__ newxyz, const int* __restrict__ knn_idx,
    const float* __restrict__ w0, const float* __restrict__ b0,
    const float* __restrict__ w1, const float* __restrict__ b1,
    const float* __restrict__ w2, const float* __restrict__ b2,
    const float* __restrict__ scales, const float* __restrict__ shifts,
    float* __restrict__ psum, float* __restrict__ psq,
    float* __restrict__ maxraw, float* __restrict__ minbuf) {
  __shared__ float act[QB * AQ];
  __shared__ float wbuf[68 * 64];
  const int bs0 = blockIdx.x * QB, t = threadIdx.x;
  build4(act, xyz, points, knn_idx, newxyz, bs0, t);
  loadw0p(wbuf, w0, t);
  __syncthreads();
  const int q = t >> 6, r = t & 63, ks = r >> 3, g = r & 7;
  float* actq = act + q * AQ;
  float acc[4][8];
  mm_unit<17>(actq, wbuf, b0, acc, ks, g);
  __syncthreads();
  write_normed(actq, acc, scales, shifts, ks, g);
  loadw64(wbuf, w1, t);
  __syncthreads();
  mm_unit<16>(actq, wbuf, b1, acc, ks, g);
  __syncthreads();
  write_normed(actq, acc, scales + 128, shifts + 128, ks, g);
  loadw_half(wbuf, w2, 0, t);
  __syncthreads();
  mm_unit<16>(actq, wbuf, b2, acc, ks, g);          // layer2 cols 0..63
  stats_reduce(acc, psum, psq, bs0 + q, 0, r);
  minmax_reduce(acc, maxraw, minbuf, bs0 + q, 0, r);
  __syncthreads();  // wbuf reads done before reload
  loadw_half(wbuf, w2, 64, t);
  __syncthreads();
  mm_unit<16>(actq, wbuf, b2 + 64, acc, ks, g);     // layer2 cols 64..127
  stats_reduce(acc, psum, psq, bs0 + q, 64, r);
  minmax_reduce(acc, maxraw, minbuf, bs0 + q, 64, r);
}

// ---------------- BN finalize ----------------
__global__ __launch_bounds__(256) void finalize_kernel(
    const float* __restrict__ psum, const float* __restrict__ psq,
    const float* __restrict__ g, const float* __restrict__ be,
    float* __restrict__ scale, float* __restrict__ shift) {
  const int ch = blockIdx.x, t = threadIdx.x;
  __shared__ float ss[256];
  __shared__ float sq[256];
  float s = 0.f, q = 0.f;
  for (int p = t; p < NBS; p += 256) {
    s += psum[(size_t)p * 128 + ch];
    q += psq[(size_t)p * 128 + ch];
  }
  ss[t] = s; sq[t] = q;
  __syncthreads();
  for (int off = 128; off >= 1; off >>= 1) {
    if (t < off) { ss[t] += ss[t + off]; sq[t] += sq[t + off]; }
    __syncthreads();
  }
  if (t == 0) {
    const float invN = 1.0f / (float)(B_ * S_ * K_);
    const float mean = ss[0] * invN;
    const float var = sq[0] * invN - mean * mean;
    const float sc = g[ch] / sqrtf(var + 1e-5f);
    scale[ch] = sc;
    shift[ch] = be[ch] - mean * sc;
  }
}

// ---------------- Final: max_k relu(sc*x+sh) ----------------
__global__ __launch_bounds__(256) void final_kernel(
    const float* __restrict__ minbuf, const float* __restrict__ scale,
    const float* __restrict__ shift, float* __restrict__ out) {
  const int i = blockIdx.x * 256 + threadIdx.x;  // < B*S*128
  const int ch = i & 127;
  const float sc = scale[ch], sh = shift[ch];
  const float mx = out[NEWXYZ_FLOATS + i];
  const float mn = minbuf[i];
  const float v = sc * (sc >= 0.f ? mx : mn) + sh;
  out[NEWXYZ_FLOATS + i] = fmaxf(v, 0.f);
}

// ---------------- host ----------------
extern "C" void kernel_launch(void* const* d_in, const int* in_sizes, int n_in,
                              void* d_out, int out_size, void* d_ws, size_t ws_size,
                              hipStream_t stream) {
  const float* xyz = (const float*)d_in[0];
  const float* points = (const float*)d_in[1];
  const float* w0 = (const float*)d_in[2];
  const float* b0 = (const float*)d_in[3];
  const float* g0 = (const float*)d_in[4];
  const float* be0 = (const float*)d_in[5];
  const float* w1 = (const float*)d_in[6];
  const float* b1 = (const float*)d_in[7];
  const float* g1 = (const float*)d_in[8];
  const float* be1 = (const float*)d_in[9];
  const float* w2 = (const float*)d_in[10];
  const float* b2 = (const float*)d_in[11];
  const float* g2 = (const float*)d_in[12];
  const float* be2 = (const float*)d_in[13];
  float* out = (float*)d_out;
  float* newxyz = out;
  float* maxraw = out + NEWXYZ_FLOATS;

  float* ws = (float*)d_ws;                  // ~27.3 MB (known to fit)
  int* knn_idx = (int*)ws;                   // B*S*K ints
  float* psum = ws + 524288;
  float* psq = psum + (size_t)NBS * 128;
  float* scales = psq + (size_t)NBS * 128;
  float* shifts = scales + 384;
  float* minbuf = shifts + 384;

  fps_kernel<<<B_, 256, 0, stream>>>(xyz, newxyz);
  knn_kernel<<<NBS / 4, 256, 0, stream>>>(xyz, newxyz, knn_idx);
  passA_kernel<<<NBS / QB, 256, 0, stream>>>(xyz, points, newxyz, knn_idx, w0, b0, psum, psq);
  finalize_kernel<<<64, 256, 0, stream>>>(psum, psq, g0, be0, scales, shifts);
  passB_kernel<<<NBS / QB, 256, 0, stream>>>(xyz, points, newxyz, knn_idx, w0, b0, w1, b1,
                                             scales, shifts, psum, psq);
  finalize_kernel<<<64, 256, 0, stream>>>(psum, psq, g1, be1, scales + 128, shifts + 128);
  passC_kernel<<<NBS / QB, 256, 0, stream>>>(xyz, points, newxyz, knn_idx, w0, b0, w1, b1,
                                             w2, b2, scales, shifts, psum, psq, maxraw, minbuf);
  finalize_kernel<<<128, 256, 0, stream>>>(psum, psq, g2, be2, scales + 256, shifts + 256);
  final_kernel<<<(B_ * S_ * 128) / 256, 256, 0, stream>>>(minbuf, scales + 256,
                                                          shifts + 256, out);
}